// Round 10
// baseline (21.611 us; speedup 1.0000x reference)
//
#include <hip/hip_runtime.h>

#define LPTS  2048   // points per row
#define NSEG  2047   // increments per row
#define TPB   256
#define STEPS 8      // segments per thread
#define NBATCH 2048
#define NWAVE (TPB / 64)

// Force a wave-uniform float into an SGPR (no-op semantics for uniform values;
// frees VGPR budget so the default 64-VGPR target doesn't spill).
__device__ __forceinline__ float rfl(float v) {
    return __int_as_float(__builtin_amdgcn_readfirstlane(__float_as_int(v)));
}

// Quotient signature state (7 floats): s[0]=a1x s[1]=a1y s[2]=a2xx s[3]=a2xy
// s[4]=a2yx s[5]=a2yy s[6]=z3 (= <WO3, a3>). Valid because a3 never feeds
// back into a1/a2 and the output only needs <WO3,a3>.

// s := s ⊗ sig(segment with increment v), z3-folded.
__device__ __forceinline__ void chen_step7(float s[7], float vx, float vy,
                                           const float WO[14], float WO78,
                                           float WO1112) {
    const float qxx = 0.5f * vx * vx;
    const float qxy = 0.5f * vx * vy;
    const float qyy = 0.5f * vy * vy;
    const float wx = fmaf(vx, (1.0f / 3.0f), s[0]);
    const float wy = fmaf(vy, (1.0f / 3.0f), s[1]);
    const float tvxx = fmaf(WO[7], vy, WO[6] * vx);
    const float tvxy = fmaf(WO[9], vy, WO[8] * vx);
    const float tvyx = fmaf(WO[11], vy, WO[10] * vx);
    const float tvyy = fmaf(WO[13], vy, WO[12] * vx);
    const float tqx = fmaf(WO[9], qyy, fmaf(WO78, qxy, WO[6] * qxx));
    const float tqy = fmaf(WO[13], qyy, fmaf(WO1112, qxy, WO[10] * qxx));
    float z1 = fmaf(s[2], tvxx, s[6]);
    z1 = fmaf(s[4], tvyx, z1);
    z1 = fmaf(wx, tqx, z1);
    float z2 = fmaf(s[5], tvyy, s[3] * tvxy);
    z2 = fmaf(wy, tqy, z2);
    s[6] = z1 + z2;
    const float ux = fmaf(vx, 0.5f, s[0]);
    const float uy = fmaf(vy, 0.5f, s[1]);
    s[2] = fmaf(ux, vx, s[2]);
    s[3] = fmaf(ux, vy, s[3]);
    s[4] = fmaf(uy, vx, s[4]);
    s[5] = fmaf(uy, vy, s[5]);
    s[0] += vx;
    s[1] += vy;
}

// b := a ⊗ b (a earlier), quotiented Chen combine. a == zeros is identity.
__device__ __forceinline__ void chen_combine7(const float a[7], float b[7],
                                              const float WO[14]) {
    const float tvxx = fmaf(WO[7], b[1], WO[6] * b[0]);
    const float tvxy = fmaf(WO[9], b[1], WO[8] * b[0]);
    const float tvyx = fmaf(WO[11], b[1], WO[10] * b[0]);
    const float tvyy = fmaf(WO[13], b[1], WO[12] * b[0]);
    const float ubx = fmaf(WO[9], b[5], fmaf(WO[8], b[4], fmaf(WO[7], b[3], WO[6] * b[2])));
    const float uby = fmaf(WO[13], b[5], fmaf(WO[12], b[4], fmaf(WO[11], b[3], WO[10] * b[2])));
    float z1 = fmaf(a[2], tvxx, a[6] + b[6]);
    z1 = fmaf(a[4], tvyx, z1);
    z1 = fmaf(a[0], ubx, z1);
    float z2 = fmaf(a[5], tvyy, a[3] * tvxy);
    z2 = fmaf(a[1], uby, z2);
    const float cxx = a[2] + fmaf(a[0], b[0], b[2]);
    const float cxy = a[3] + fmaf(a[0], b[1], b[3]);
    const float cyx = a[4] + fmaf(a[1], b[0], b[4]);
    const float cyy = a[5] + fmaf(a[1], b[1], b[5]);
    b[0] = a[0] + b[0];
    b[1] = a[1] + b[1];
    b[2] = cxx;
    b[3] = cxy;
    b[4] = cyx;
    b[5] = cyy;
    b[6] = z1 + z2;
}

// pointwise MLP 1 -> 8 -> 2 (ReLU between)
__device__ __forceinline__ void augment(float x,
                                        const float W1[8], const float B1[8],
                                        const float W2x[8], const float W2y[8],
                                        float B2x, float B2y,
                                        float& px, float& py) {
    float ox = B2x, oy = B2y;
#pragma unroll
    for (int c = 0; c < 8; ++c) {
        float h = fmaxf(fmaf(W1[c], x, B1[c]), 0.0f);
        ox = fmaf(W2x[c], h, ox);
        oy = fmaf(W2y[c], h, oy);
    }
    px = ox;
    py = oy;
}

__global__ void sig_scan_kernel(
    const float* __restrict__ x, const float* __restrict__ w1,
    const float* __restrict__ b1, const float* __restrict__ w2,
    const float* __restrict__ b2, const float* __restrict__ wout,
    float* __restrict__ out) {
    __shared__ float wsum[NWAVE][8];

    const int t = threadIdx.x;
    const int lane = t & 63;
    const int wv = t >> 6;
    const int brow = blockIdx.x;
    const float* __restrict__ xrow = x + (size_t)brow * LPTS;

    // uniform weights -> pinned to SGPRs via readfirstlane
    float W1[8], B1[8], W2x[8], W2y[8];
#pragma unroll
    for (int c = 0; c < 8; ++c) {
        W1[c] = rfl(w1[c]);
        B1[c] = rfl(b1[c]);
        W2x[c] = rfl(w2[c]);
        W2y[c] = rfl(w2[8 + c]);
    }
    const float B2x = rfl(b2[0]), B2y = rfl(b2[1]);
    float WO[14];
#pragma unroll
    for (int i = 0; i < 14; ++i) WO[i] = rfl(wout[i]);
    const float WO78 = WO[7] + WO[8];
    const float WO1112 = WO[11] + WO[12];

    // ---- phase 1: load 9 points, augment, increments, local 7-state sig ----
    const int n0 = t * STEPS;
    const float4 xa = *reinterpret_cast<const float4*>(xrow + n0);
    const float4 xb = *reinterpret_cast<const float4*>(xrow + n0 + 4);
    const int ib = (n0 + STEPS > LPTS - 1) ? (LPTS - 1) : (n0 + STEPS);
    const float x8 = xrow[ib];  // clamped -> v=0 identity for last thread
    const float xv[STEPS + 1] = {xa.x, xa.y, xa.z, xa.w,
                                 xb.x, xb.y, xb.z, xb.w, x8};

    float vx[STEPS], vy[STEPS];
    float s[7] = {0, 0, 0, 0, 0, 0, 0};
    float ppx, ppy;
    augment(xv[0], W1, B1, W2x, W2y, B2x, B2y, ppx, ppy);
#pragma unroll
    for (int k = 0; k < STEPS; ++k) {
        float px, py;
        augment(xv[k + 1], W1, B1, W2x, W2y, B2x, B2y, px, py);
        vx[k] = px - ppx;
        vy[k] = py - ppy;
        ppx = px;
        ppy = py;
        chen_step7(s, vx[k], vy[k], WO, WO78, WO1112);
    }

    // ---- phase 2a: wave64 inclusive shuffle scan (7-wide) ----
#pragma unroll
    for (int off = 1; off < 64; off <<= 1) {
        float p[7];
#pragma unroll
        for (int i = 0; i < 7; ++i) p[i] = __shfl_up(s[i], (unsigned)off);
        if (lane >= off) chen_combine7(p, s, WO);
    }

    // ---- phase 2b: cross-wave combine (one barrier, broadcast reads) ----
    if (lane == 63) {
#pragma unroll
        for (int i = 0; i < 7; ++i) wsum[wv][i] = s[i];
    }
    __syncthreads();

    float a[7];  // exclusive carry
    {
        float e[7];
#pragma unroll
        for (int i = 0; i < 7; ++i) e[i] = __shfl_up(s[i], 1u);
#pragma unroll
        for (int i = 0; i < 7; ++i) a[i] = (lane == 0) ? 0.0f : e[i];
    }
    for (int w = wv - 1; w >= 0; --w) {
        float tw[7];
#pragma unroll
        for (int i = 0; i < 7; ++i) tw[i] = wsum[w][i];
        chen_combine7(tw, a, WO);
    }

    // ---- phase 3: replay with carry, project, direct store ----
    float* __restrict__ orow = out + (size_t)brow * NSEG;
#pragma unroll
    for (int k = 0; k < STEPS; ++k) {
        chen_step7(a, vx[k], vy[k], WO, WO78, WO1112);
        float o = a[6];
        o = fmaf(WO[0], a[0], o);
        o = fmaf(WO[1], a[1], o);
        o = fmaf(WO[2], a[2], o);
        o = fmaf(WO[3], a[3], o);
        o = fmaf(WO[4], a[4], o);
        o = fmaf(WO[5], a[5], o);
        const int n = n0 + k;
        if (n < NSEG) orow[n] = o;
    }
}

extern "C" void kernel_launch(void* const* d_in, const int* in_sizes, int n_in,
                              void* d_out, int out_size, void* d_ws, size_t ws_size,
                              hipStream_t stream) {
    const float* x  = (const float*)d_in[0];
    const float* w1 = (const float*)d_in[1];
    const float* b1 = (const float*)d_in[2];
    const float* w2 = (const float*)d_in[3];
    const float* b2 = (const float*)d_in[4];
    const float* wo = (const float*)d_in[5];
    float* out = (float*)d_out;
    sig_scan_kernel<<<NBATCH, TPB, 0, stream>>>(x, w1, b1, w2, b2, wo, out);
}

// Round 11
// 21.429 us; speedup vs baseline: 1.0085x; 1.0085x over previous
//
#include <hip/hip_runtime.h>

#define LPTS  2048   // points per row
#define NSEG  2047   // increments per row
#define TPB   256
#define STEPS 8      // segments per thread
#define NBATCH 2048
#define NWAVE (TPB / 64)

// DPP lane-shift returning 0 for lanes without a source (bound_ctrl) or in
// masked-off rows (row_mask). Zero state == identity for chen_combine7.
template <int CTRL, int RMASK, bool BC>
__device__ __forceinline__ float dpp_f(float s) {
    return __int_as_float(__builtin_amdgcn_update_dpp(
        0, __float_as_int(s), CTRL, RMASK, 0xF, BC));
}

// Quotient signature state (7 floats): s[0]=a1x s[1]=a1y s[2]=a2xx s[3]=a2xy
// s[4]=a2yx s[5]=a2yy s[6]=z3 (= <WO3, a3>). Valid because a3 never feeds
// back into a1/a2 and the output only needs <WO3,a3>.

// s := s ⊗ sig(segment with increment v), z3-folded.
__device__ __forceinline__ void chen_step7(float s[7], float vx, float vy,
                                           const float WO[14], float WO78,
                                           float WO1112) {
    const float qxx = 0.5f * vx * vx;
    const float qxy = 0.5f * vx * vy;
    const float qyy = 0.5f * vy * vy;
    const float wx = fmaf(vx, (1.0f / 3.0f), s[0]);
    const float wy = fmaf(vy, (1.0f / 3.0f), s[1]);
    const float tvxx = fmaf(WO[7], vy, WO[6] * vx);
    const float tvxy = fmaf(WO[9], vy, WO[8] * vx);
    const float tvyx = fmaf(WO[11], vy, WO[10] * vx);
    const float tvyy = fmaf(WO[13], vy, WO[12] * vx);
    const float tqx = fmaf(WO[9], qyy, fmaf(WO78, qxy, WO[6] * qxx));
    const float tqy = fmaf(WO[13], qyy, fmaf(WO1112, qxy, WO[10] * qxx));
    float z1 = fmaf(s[2], tvxx, s[6]);
    z1 = fmaf(s[4], tvyx, z1);
    z1 = fmaf(wx, tqx, z1);
    float z2 = fmaf(s[5], tvyy, s[3] * tvxy);
    z2 = fmaf(wy, tqy, z2);
    s[6] = z1 + z2;
    const float ux = fmaf(vx, 0.5f, s[0]);
    const float uy = fmaf(vy, 0.5f, s[1]);
    s[2] = fmaf(ux, vx, s[2]);
    s[3] = fmaf(ux, vy, s[3]);
    s[4] = fmaf(uy, vx, s[4]);
    s[5] = fmaf(uy, vy, s[5]);
    s[0] += vx;
    s[1] += vy;
}

// b := a ⊗ b (a earlier), quotiented Chen combine. a == zeros is identity.
__device__ __forceinline__ void chen_combine7(const float a[7], float b[7],
                                              const float WO[14]) {
    const float tvxx = fmaf(WO[7], b[1], WO[6] * b[0]);
    const float tvxy = fmaf(WO[9], b[1], WO[8] * b[0]);
    const float tvyx = fmaf(WO[11], b[1], WO[10] * b[0]);
    const float tvyy = fmaf(WO[13], b[1], WO[12] * b[0]);
    const float ubx = fmaf(WO[9], b[5], fmaf(WO[8], b[4], fmaf(WO[7], b[3], WO[6] * b[2])));
    const float uby = fmaf(WO[13], b[5], fmaf(WO[12], b[4], fmaf(WO[11], b[3], WO[10] * b[2])));
    float z1 = fmaf(a[2], tvxx, a[6] + b[6]);
    z1 = fmaf(a[4], tvyx, z1);
    z1 = fmaf(a[0], ubx, z1);
    float z2 = fmaf(a[5], tvyy, a[3] * tvxy);
    z2 = fmaf(a[1], uby, z2);
    const float cxx = a[2] + fmaf(a[0], b[0], b[2]);
    const float cxy = a[3] + fmaf(a[0], b[1], b[3]);
    const float cyx = a[4] + fmaf(a[1], b[0], b[4]);
    const float cyy = a[5] + fmaf(a[1], b[1], b[5]);
    b[0] = a[0] + b[0];
    b[1] = a[1] + b[1];
    b[2] = cxx;
    b[3] = cxy;
    b[4] = cyx;
    b[5] = cyy;
    b[6] = z1 + z2;
}

// pointwise MLP 1 -> 8 -> 2 (ReLU between)
__device__ __forceinline__ void augment(float x,
                                        const float W1[8], const float B1[8],
                                        const float W2x[8], const float W2y[8],
                                        float B2x, float B2y,
                                        float& px, float& py) {
    float ox = B2x, oy = B2y;
#pragma unroll
    for (int c = 0; c < 8; ++c) {
        float h = fmaxf(fmaf(W1[c], x, B1[c]), 0.0f);
        ox = fmaf(W2x[c], h, ox);
        oy = fmaf(W2y[c], h, oy);
    }
    px = ox;
    py = oy;
}

// One DPP scan round: p = lane-shift(s) (0 where no source), s = p ⊗ s.
#define SCAN_ROUND(CTRL, RMASK, BC)                                     \
    {                                                                   \
        float p[7];                                                     \
        _Pragma("unroll")                                               \
        for (int i = 0; i < 7; ++i) p[i] = dpp_f<CTRL, RMASK, BC>(s[i]); \
        chen_combine7(p, s, WO);                                        \
    }

__global__ void sig_scan_kernel(
    const float* __restrict__ x, const float* __restrict__ w1,
    const float* __restrict__ b1, const float* __restrict__ w2,
    const float* __restrict__ b2, const float* __restrict__ wout,
    float* __restrict__ out) {
    __shared__ float wsum[NWAVE][8];

    const int t = threadIdx.x;
    const int lane = t & 63;
    const int wv = t >> 6;
    const int brow = blockIdx.x;
    const float* __restrict__ xrow = x + (size_t)brow * LPTS;

    // uniform weights (uniform addresses -> s_load)
    float W1[8], B1[8], W2x[8], W2y[8];
#pragma unroll
    for (int c = 0; c < 8; ++c) {
        W1[c] = w1[c];
        B1[c] = b1[c];
        W2x[c] = w2[c];
        W2y[c] = w2[8 + c];
    }
    const float B2x = b2[0], B2y = b2[1];
    float WO[14];
#pragma unroll
    for (int i = 0; i < 14; ++i) WO[i] = wout[i];
    const float WO78 = WO[7] + WO[8];
    const float WO1112 = WO[11] + WO[12];

    // ---- phase 1: load 9 points, augment, increments, local 7-state sig ----
    const int n0 = t * STEPS;
    const float4 xa = *reinterpret_cast<const float4*>(xrow + n0);
    const float4 xb = *reinterpret_cast<const float4*>(xrow + n0 + 4);
    const int ib = (n0 + STEPS > LPTS - 1) ? (LPTS - 1) : (n0 + STEPS);
    const float x8 = xrow[ib];  // clamped -> v=0 identity for last thread
    const float xv[STEPS + 1] = {xa.x, xa.y, xa.z, xa.w,
                                 xb.x, xb.y, xb.z, xb.w, x8};

    float vx[STEPS], vy[STEPS];
    float s[7] = {0, 0, 0, 0, 0, 0, 0};
    float ppx, ppy;
    augment(xv[0], W1, B1, W2x, W2y, B2x, B2y, ppx, ppy);
#pragma unroll
    for (int k = 0; k < STEPS; ++k) {
        float px, py;
        augment(xv[k + 1], W1, B1, W2x, W2y, B2x, B2y, px, py);
        vx[k] = px - ppx;
        vy[k] = py - ppy;
        ppx = px;
        ppy = py;
        chen_step7(s, vx[k], vy[k], WO, WO78, WO1112);
    }

    // ---- phase 2a: wave64 inclusive scan, pure DPP (no LDS pipe) ----
    SCAN_ROUND(0x111, 0xF, true)   // row_shr:1
    SCAN_ROUND(0x112, 0xF, true)   // row_shr:2
    SCAN_ROUND(0x114, 0xF, true)   // row_shr:4
    SCAN_ROUND(0x118, 0xF, true)   // row_shr:8
    SCAN_ROUND(0x142, 0xA, false)  // row_bcast15 -> rows 1,3
    SCAN_ROUND(0x143, 0xC, false)  // row_bcast31 -> rows 2,3

    // ---- phase 2b: cross-wave combine (one barrier, broadcast reads) ----
    if (lane == 63) {
#pragma unroll
        for (int i = 0; i < 7; ++i) wsum[wv][i] = s[i];
    }
    __syncthreads();

    // exclusive carry: wave_shr:1 (lane 0 gets identity automatically)
    float a[7];
#pragma unroll
    for (int i = 0; i < 7; ++i) a[i] = dpp_f<0x138, 0xF, true>(s[i]);
    for (int w = wv - 1; w >= 0; --w) {
        float tw[7];
#pragma unroll
        for (int i = 0; i < 7; ++i) tw[i] = wsum[w][i];
        chen_combine7(tw, a, WO);
    }

    // ---- phase 3: replay with carry, project, direct store ----
    float* __restrict__ orow = out + (size_t)brow * NSEG;
#pragma unroll
    for (int k = 0; k < STEPS; ++k) {
        chen_step7(a, vx[k], vy[k], WO, WO78, WO1112);
        float o = a[6];
        o = fmaf(WO[0], a[0], o);
        o = fmaf(WO[1], a[1], o);
        o = fmaf(WO[2], a[2], o);
        o = fmaf(WO[3], a[3], o);
        o = fmaf(WO[4], a[4], o);
        o = fmaf(WO[5], a[5], o);
        const int n = n0 + k;
        if (n < NSEG) orow[n] = o;
    }
}

extern "C" void kernel_launch(void* const* d_in, const int* in_sizes, int n_in,
                              void* d_out, int out_size, void* d_ws, size_t ws_size,
                              hipStream_t stream) {
    const float* x  = (const float*)d_in[0];
    const float* w1 = (const float*)d_in[1];
    const float* b1 = (const float*)d_in[2];
    const float* w2 = (const float*)d_in[3];
    const float* b2 = (const float*)d_in[4];
    const float* wo = (const float*)d_in[5];
    float* out = (float*)d_out;
    sig_scan_kernel<<<NBATCH, TPB, 0, stream>>>(x, w1, b1, w2, b2, wo, out);
}